// Round 5
// baseline (321.340 us; speedup 1.0000x reference)
//
#include <hip/hip_runtime.h>

// ---------------------------------------------------------------------------
// GAT 2-layer encoder. N=100k nodes, E=1.6M edges, 128->128(relu)->64.
//   a_dst = x . (W_dst @ att_dst)  (h_dst never materialized)
//   CSR-by-dst via two-level counting sort (LDS-staged coalesced scatter)
//   MFMA f16 GEMM (16x16x32), W pre-packed to fragment layout, fused aS/aD
//   aggregation: R1 form — 2 nodes/wave, aS gather first, double-buffered
//   NEW: agg1+gemm2 fused per 64-node block (h1 rows stay in LDS; h1h HBM
//   round-trip eliminated). 6 dispatches.
// ---------------------------------------------------------------------------

typedef unsigned long long u64;
typedef float v4f __attribute__((ext_vector_type(4)));
typedef _Float16 v2h __attribute__((ext_vector_type(2)));
typedef __fp16 h8 __attribute__((ext_vector_type(8)));

#define SEL_LO 0x01000504u   // (a.f16lo, b.f16lo)
#define SEL_HI 0x03020706u   // (a.f16hi, b.f16hi)

__device__ __forceinline__ void ntstore4(float* p, v4f v) {
    __builtin_nontemporal_store(v, (v4f*)p);
}
__device__ __forceinline__ unsigned h2pack(float a, float b) {  // RNE
    v2h h;
    h.x = (_Float16)a;
    h.y = (_Float16)b;
    return __builtin_bit_cast(unsigned, h);
}
__device__ __forceinline__ float fdot2u(unsigned u, v2h w, float acc) {
    return __builtin_amdgcn_fdot2(__builtin_bit_cast(v2h, u), w, acc, false);
}
__device__ __forceinline__ v2h pkrtz(float a, float b) {
    return __builtin_bit_cast(v2h, __builtin_amdgcn_cvt_pkrtz(a, b));
}

// ---- fused setup: per-block dst histograms + W packing + matvecs ----------
__device__ void matvec_body(const float* __restrict__ W, const float* __restrict__ a,
                            float* __restrict__ out, int cols, int row) {
    int lane = threadIdx.x & 63;
    float s = 0.f;
    for (int j = lane; j < cols; j += 64) s += W[row * cols + j] * a[j];
#pragma unroll
    for (int o = 32; o; o >>= 1) s += __shfl_xor(s, o, 64);
    if (lane == 0) out[row] = s;
}

// pack W [128 x C] f32 -> MFMA B-fragment order, f16:
//   Wp[(t*NT + tile)*64 + lane] = 8 f16 { W[32t+(lane>>4)*8+j][tile*16+(lane&15)] }
template <int C>
__device__ void packw_body(const float* __restrict__ W, uint4* __restrict__ Wp) {
    constexpr int NT = C / 16;
    const int total = 4 * NT * 64;
    for (int e = threadIdx.x; e < total; e += 256) {
        int lane = e & 63;
        int ti = (e >> 6) % NT;
        int t = (e >> 6) / NT;
        int k0 = 32 * t + (lane >> 4) * 8;
        int n = ti * 16 + (lane & 15);
        unsigned u[4];
#pragma unroll
        for (int p = 0; p < 4; ++p)
            u[p] = h2pack(W[(size_t)(k0 + 2 * p) * C + n], W[(size_t)(k0 + 2 * p + 1) * C + n]);
        Wp[e] = make_uint4(u[0], u[1], u[2], u[3]);
    }
}

__global__ __launch_bounds__(256) void setup_kernel(
    const int* __restrict__ dst, int* __restrict__ hist, int E, int nbE,
    const float* __restrict__ W1s, uint4* __restrict__ wp1,
    const float* __restrict__ W2s, uint4* __restrict__ wp2,
    const float* __restrict__ W1d, const float* __restrict__ att1d, float* __restrict__ watt1,
    const float* __restrict__ W2d, const float* __restrict__ att2d, float* __restrict__ watt2) {
    int b = blockIdx.x;
    if (b < nbE) {
        __shared__ int h[256];
        h[threadIdx.x] = 0;
        __syncthreads();
        int base = b * 4096;
        int lim = min(base + 4096, E);
        for (int i = base + threadIdx.x; i < lim; i += 256)
            atomicAdd(&h[__builtin_nontemporal_load(dst + i) >> 9], 1);
        __syncthreads();
        __builtin_nontemporal_store(h[threadIdx.x], hist + b * 256 + threadIdx.x);
    } else if (b == nbE) {
        packw_body<128>(W1s, wp1);
    } else if (b == nbE + 1) {
        packw_body<64>(W2s, wp2);
    } else if (b < nbE + 34) {
        matvec_body(W1d, att1d, watt1, 128, (b - nbE - 2) * 4 + (threadIdx.x >> 6));
    } else {
        matvec_body(W2d, att2d, watt2, 64, (b - nbE - 34) * 4 + (threadIdx.x >> 6));
    }
}

__global__ __launch_bounds__(256) void bscan_kernel(const int* __restrict__ hist, int nbE,
                                                    int* __restrict__ bbase,
                                                    int* __restrict__ gcur,
                                                    int* __restrict__ offs, int N, int E) {
    __shared__ int s[256];
    int t = threadIdx.x;
    int v = 0;
#pragma unroll 4
    for (int b = 0; b < nbE; ++b) v += hist[b * 256 + t];
    s[t] = v;
    __syncthreads();
    for (int o = 1; o < 256; o <<= 1) {
        int u = (t >= o) ? s[t - o] : 0;
        __syncthreads();
        s[t] += u;
        __syncthreads();
    }
    int excl = s[t] - v;
    bbase[t] = excl;
    gcur[t] = excl;
    if (t == 255) { bbase[256] = E; offs[N] = E; }
}

// rank within block, stage pairs in LDS in bucket order, write coalesced runs
__device__ void scatter_body(const int* __restrict__ src, const int* __restrict__ dst,
                             int* __restrict__ gcur, u64* __restrict__ pairs, int E,
                             int blk, char* smem) {
    int* h = (int*)smem;
    int* sbase = h + 256;
    int* rbase = h + 512;
    u64* buf = (u64*)(smem + 3072);
    const int tid = threadIdx.x;
    h[tid] = 0;
    __syncthreads();
    const int base = blk * 4096;
    const int lim = min(4096, E - base);
    u64 pv[16];
    int rk[16];
    int bk[16];
#pragma unroll 16
    for (int k = 0; k < 16; ++k) {
        int i = base + k * 256 + tid;
        if (i < E) {
            int d = __builtin_nontemporal_load(dst + i);
            int b = d >> 9;
            bk[k] = b;
            pv[k] = ((u64)(unsigned)d << 32) | (unsigned)__builtin_nontemporal_load(src + i);
            rk[k] = atomicAdd(&h[b], 1);
        } else {
            bk[k] = -1;
        }
    }
    __syncthreads();
    const int v = h[tid];
    sbase[tid] = v;
    __syncthreads();
    for (int o = 1; o < 256; o <<= 1) {
        int uu = (tid >= o) ? sbase[tid - o] : 0;
        __syncthreads();
        sbase[tid] += uu;
        __syncthreads();
    }
    const int excl = sbase[tid] - v;
    rbase[tid] = v ? atomicAdd(&gcur[tid], v) : 0;
    __syncthreads();
    sbase[tid] = excl;
    __syncthreads();
#pragma unroll 16
    for (int k = 0; k < 16; ++k)
        if (bk[k] >= 0) buf[sbase[bk[k]] + rk[k]] = pv[k];
    __syncthreads();
    for (int i = tid; i < lim; i += 256) {
        u64 p = buf[i];
        int b = (int)(p >> 41);                       // dst>>9
        __builtin_nontemporal_store(p, pairs + (size_t)rbase[b] + (i - sbase[b]));
    }
}

__global__ __launch_bounds__(512) void bsort_kernel(const u64* __restrict__ pairs,
                                                    const int* __restrict__ bbase,
                                                    int* __restrict__ offs,
                                                    int* __restrict__ srcs, int N) {
    __shared__ int h[512];
    __shared__ int cur[512];
    const int t = threadIdx.x;
    const int b = blockIdx.x;
    const int beg = bbase[b], end = bbase[b + 1];
    h[t] = 0;
    __syncthreads();
    for (int i = beg + t; i < end; i += 512)
        atomicAdd(&h[(int)(__builtin_nontemporal_load(pairs + i) >> 32) & 511], 1);
    __syncthreads();
    int v = h[t];
    cur[t] = v;
    __syncthreads();
    for (int o = 1; o < 512; o <<= 1) {
        int u = (t >= o) ? cur[t - o] : 0;
        __syncthreads();
        cur[t] += u;
        __syncthreads();
    }
    int pos0 = beg + cur[t] - v;
    __syncthreads();
    cur[t] = pos0;
    int g = (b << 9) + t;
    if (g < N) offs[g] = pos0;
    __syncthreads();
    for (int i = beg + t; i < end; i += 512) {
        u64 p = __builtin_nontemporal_load(pairs + i);
        int local = (int)(p >> 32) & 511;
        int pp = atomicAdd(&cur[local], 1);
        srcs[pp] = (int)(p & 0xffffffffu);
    }
}

// MFMA GEMM: H[M,C] (f16) = X[M,128] @ W; fused aS = H.attS, aD = X.wda.
// Layouts (m89-verified): A[m=lane&15][k=quad*8+j]; B[k=quad*8+j][n=lane&15];
// D col=lane&15, row=quad*4+reg.
template <int C, bool XF16>
__device__ void gemm_body(int blk, const void* __restrict__ Xv, const uint4* __restrict__ Wp,
                          const float* __restrict__ attS, const float* __restrict__ wda,
                          unsigned* __restrict__ H, float* __restrict__ aS,
                          float* __restrict__ aD, int M, _Float16* hsAll) {
    constexpr int NT = C / 16;
    const int tid = threadIdx.x;
    const int w = tid >> 6;
    const int lane = tid & 63;
    const int l15 = lane & 15;
    const int q = lane >> 4;
    const int mb = blk * 64 + w * 16;
    const int m = mb + l15;
    const bool mv = m < M;

    v4f acc[NT];
#pragma unroll
    for (int n = 0; n < NT; ++n) acc[n] = (v4f)(0.f);
    float pd = 0.f;
    uint4 afu[4];

    if constexpr (XF16) {
        const uint4* Xp = (const uint4*)Xv + (size_t)m * 16;   // 128 f16 = 16 uint4
#pragma unroll
        for (int t = 0; t < 4; ++t) {
            uint4 u = make_uint4(0u, 0u, 0u, 0u);
            if (mv) u = Xp[4 * t + q];
            afu[t] = u;
            const float* wdp = wda + 32 * t + 8 * q;
            pd = fdot2u(u.x, pkrtz(wdp[0], wdp[1]), pd);
            pd = fdot2u(u.y, pkrtz(wdp[2], wdp[3]), pd);
            pd = fdot2u(u.z, pkrtz(wdp[4], wdp[5]), pd);
            pd = fdot2u(u.w, pkrtz(wdp[6], wdp[7]), pd);
        }
    } else {
        const float* Xp = (const float*)Xv + (size_t)m * 128;
#pragma unroll
        for (int t = 0; t < 4; ++t) {
            float4 x0 = make_float4(0.f, 0.f, 0.f, 0.f);
            float4 x1 = x0;
            if (mv) {
                x0 = *(const float4*)(Xp + 32 * t + 8 * q);
                x1 = *(const float4*)(Xp + 32 * t + 8 * q + 4);
            }
            const float* wdp = wda + 32 * t + 8 * q;
            pd += x0.x * wdp[0] + x0.y * wdp[1] + x0.z * wdp[2] + x0.w * wdp[3] +
                  x1.x * wdp[4] + x1.y * wdp[5] + x1.z * wdp[6] + x1.w * wdp[7];
            afu[t] = make_uint4(h2pack(x0.x, x0.y), h2pack(x0.z, x0.w),
                                h2pack(x1.x, x1.y), h2pack(x1.z, x1.w));
        }
    }

    // MFMA main loop
#pragma unroll
    for (int t = 0; t < 4; ++t) {
        h8 a = __builtin_bit_cast(h8, afu[t]);
        const uint4* wp = Wp + (size_t)t * NT * 64 + lane;
#pragma unroll
        for (int n = 0; n < NT; ++n) {
            h8 b = __builtin_bit_cast(h8, wp[n * 64]);
            acc[n] = __builtin_amdgcn_mfma_f32_16x16x32_f16(a, b, acc[n], 0, 0, 0);
        }
    }

    // aD: reduce per-lane partial over quads (lanes sharing m)
    pd += __shfl_xor(pd, 16, 64);
    pd += __shfl_xor(pd, 32, 64);
    if (q == 0 && mv) aD[m] = pd;

    // aS: dot accumulators with attS, reduce across the 16 cols (same quad)
    float as4[4] = {0.f, 0.f, 0.f, 0.f};
#pragma unroll
    for (int n = 0; n < NT; ++n) {
        float av = attS[n * 16 + l15];
#pragma unroll
        for (int r = 0; r < 4; ++r) as4[r] += acc[n][r] * av;
    }
#pragma unroll
    for (int r = 0; r < 4; ++r) {
#pragma unroll
        for (int o = 1; o < 16; o <<= 1) as4[r] += __shfl_xor(as4[r], o, 64);
    }
    if (l15 == 0) {
#pragma unroll
        for (int r = 0; r < 4; ++r) {
            int row = mb + q * 4 + r;
            if (row < M) aS[row] = as4[r];
        }
    }

    // H store: f16 via per-wave LDS transpose (wave-local; no barrier needed)
    _Float16* hp = hsAll + w * (16 * 136);
#pragma unroll
    for (int n = 0; n < NT; ++n)
#pragma unroll
        for (int r = 0; r < 4; ++r)
            hp[(q * 4 + r) * 136 + n * 16 + l15] = (_Float16)acc[n][r];

    constexpr int CH = C / 32;              // 64-B chunks per row
    if (lane < 16 * CH) {
        int row = lane / CH;
        int ch = lane % CH;
        const uint4* rp = (const uint4*)(hp + row * 136 + ch * 32);
        uint4 v0 = rp[0], v1 = rp[1], v2 = rp[2], v3 = rp[3];
        int gr = mb + row;
        if (gr < M) {
            uint4* op = (uint4*)(H + (size_t)gr * (C / 2)) + ch * 4;
            op[0] = v0; op[1] = v1; op[2] = v2; op[3] = v3;
        }
    }
}

// fused: bscatter blocks [0,nbS) | gemm1 blocks [nbS, nbS+gblk)
__global__ __launch_bounds__(256) void scatter_gemm_kernel(
    const int* __restrict__ src, const int* __restrict__ dst, int* __restrict__ gcur,
    u64* __restrict__ pairs, int E, int nbS,
    const void* __restrict__ Xv, const uint4* __restrict__ Wp,
    const float* __restrict__ attS, const float* __restrict__ wda,
    unsigned* __restrict__ H, float* __restrict__ aS, float* __restrict__ aD, int M) {
    __shared__ __align__(16) char smem[35840];
    int b = blockIdx.x;
    if (b < nbS) scatter_body(src, dst, gcur, pairs, E, b, smem);
    else gemm_body<128, false>(b - nbS, Xv, Wp, attS, wda, H, aS, aD, M, (_Float16*)smem);
}

// Segment softmax + weighted aggregation (R1 form, standalone — used for agg2).
template <int C, bool RELU, bool F16OUT, bool NTOUT>
__global__ __launch_bounds__(256) void aggregate_kernel(
    const int* __restrict__ offs, const int* __restrict__ srcs,
    const unsigned* __restrict__ hsrc, const float* __restrict__ aS,
    const float* __restrict__ aD, const float* __restrict__ bias,
    void* __restrict__ outv, int n) {
    const int lane = threadIdx.x & 63;
    const int sl = lane & 31;            // slot within half
    const int hb = lane & 32;            // half base (0 or 32) for shuffles
    const int g = (lane >> 4) & 1;       // group within half
    const int l = lane & 15;
    int node = (int)((blockIdx.x * blockDim.x + threadIdx.x) >> 5);  // 2 nodes/wave
    if (node >= n) return;

    const int beg = offs[node], end = offs[node + 1];
    const int deg = end - beg;
    const float ad = aD[node];

    constexpr int LW = C / 32;           // dwords per lane per gathered row
    constexpr int NA = C / 16;           // f32 accumulators per lane
    float acc[NA];
#pragma unroll
    for (int i = 0; i < NA; ++i) acc[i] = 0.f;

    int sj = 0;
    float u = 0.f;

    auto ldrow = [&](int s, unsigned* r) {
        if constexpr (C == 128) {
            uint4 v = ((const uint4*)(hsrc + ((size_t)s << 6)))[l];
            r[0] = v.x; r[1] = v.y; r[2] = v.z; r[3] = v.w;
        } else {
            uint2 v = ((const uint2*)(hsrc + ((size_t)s << 5)))[l];
            r[0] = v.x; r[1] = v.y;
        }
    };
    auto issue = [&](int j, unsigned (*buf)[LW]) {
        int e0 = hb + j * 8 + g;
        int s0 = __shfl(sj, e0, 64);
        int s1 = __shfl(sj, e0 + 2, 64);
        int s2 = __shfl(sj, e0 + 4, 64);
        int s3 = __shfl(sj, e0 + 6, 64);
        ldrow(s0, buf[0]);
        ldrow(s1, buf[1]);
        ldrow(s2, buf[2]);
        ldrow(s3, buf[3]);
    };
    auto compute = [&](int j, unsigned (*buf)[LW], float inv) {
        int e0 = hb + j * 8 + g;
        float w0 = __shfl(u, e0, 64) * inv, w1 = __shfl(u, e0 + 2, 64) * inv;
        float w2 = __shfl(u, e0 + 4, 64) * inv, w3 = __shfl(u, e0 + 6, 64) * inv;
        v2h w01 = pkrtz(w0, w1);
        v2h w23 = pkrtz(w2, w3);
#pragma unroll
        for (int ii = 0; ii < LW; ++ii) {
            acc[2 * ii] = fdot2u(__builtin_amdgcn_perm(buf[0][ii], buf[1][ii], SEL_LO), w01,
                          fdot2u(__builtin_amdgcn_perm(buf[2][ii], buf[3][ii], SEL_LO), w23, acc[2 * ii]));
            acc[2 * ii + 1] = fdot2u(__builtin_amdgcn_perm(buf[0][ii], buf[1][ii], SEL_HI), w01,
                              fdot2u(__builtin_amdgcn_perm(buf[2][ii], buf[3][ii], SEL_HI), w23, acc[2 * ii + 1]));
        }
    };

    unsigned A0[4][LW], A1[4][LW];

    if (deg <= 32) {
        int i = beg + sl;
        if (i < end) {
            sj = __builtin_nontemporal_load(srcs + i);
            float lg = aS[sj] + ad;
            lg = (lg > 0.f) ? lg : 0.2f * lg;
            u = __expf(lg);
        }
        int jm = (deg + 7) >> 3;
        if (jm > 0) issue(0, A0);
        if (jm > 1) issue(1, A1);
        float s = u;
#pragma unroll
        for (int o = 16; o; o >>= 1) s += __shfl_xor(s, o, 64);
        float inv = 1.f / (s + 1e-16f);
        if (jm > 0) { compute(0, A0, inv); if (jm > 2) issue(2, A0); }
        if (jm > 1) { compute(1, A1, inv); if (jm > 3) issue(3, A1); }
        if (jm > 2) compute(2, A0, inv);
        if (jm > 3) compute(3, A1, inv);
    } else {
        float m = -INFINITY;
        for (int i = beg + sl; i < end; i += 32) {
            float lg = aS[srcs[i]] + ad;
            lg = (lg > 0.f) ? lg : 0.2f * lg;
            m = fmaxf(m, lg);
        }
#pragma unroll
        for (int o = 16; o; o >>= 1) m = fmaxf(m, __shfl_xor(m, o, 64));
        float ssum = 0.f;
        for (int i = beg + sl; i < end; i += 32) {
            float lg = aS[srcs[i]] + ad;
            lg = (lg > 0.f) ? lg : 0.2f * lg;
            ssum += __expf(lg - m);
        }
#pragma unroll
        for (int o = 16; o; o >>= 1) ssum += __shfl_xor(ssum, o, 64);
        float inv = 1.f / (ssum + 1e-16f);
        for (int base = beg; base < end; base += 32) {
            int i = base + sl;
            sj = 0;
            u = 0.f;
            if (i < end) {
                sj = srcs[i];
                float lg = aS[sj] + ad;
                lg = (lg > 0.f) ? lg : 0.2f * lg;
                u = __expf(lg - m);
            }
            int cnt = min(32, end - base);
            int cj = (cnt + 7) >> 3;
            if (cj > 0) issue(0, A0);
            if (cj > 1) issue(1, A1);
            if (cj > 0) { compute(0, A0, inv); if (cj > 2) issue(2, A0); }
            if (cj > 1) { compute(1, A1, inv); if (cj > 3) issue(3, A1); }
            if (cj > 2) compute(2, A0, inv);
            if (cj > 3) compute(3, A1, inv);
        }
    }

#pragma unroll
    for (int i = 0; i < NA; ++i) acc[i] += __shfl_xor(acc[i], 16, 64);

    if (sl < 16) {
        float o[NA];
        const float* bp = bias + l * NA;
#pragma unroll
        for (int i = 0; i < NA; ++i) {
            o[i] = acc[i] + bp[i];
            if (RELU) o[i] = fmaxf(o[i], 0.f);
        }
        if constexpr (F16OUT) {
            unsigned uo[NA / 2];
#pragma unroll
            for (int k = 0; k < NA / 2; ++k) uo[k] = h2pack(o[2 * k], o[2 * k + 1]);
            unsigned* op = (unsigned*)outv + (size_t)node * (C / 2) + l * (NA / 2);
            if constexpr (NA == 8) *(uint4*)op = make_uint4(uo[0], uo[1], uo[2], uo[3]);
            else *(uint2*)op = make_uint2(uo[0], uo[1]);
        } else {
            float* op = (float*)outv + (size_t)node * C + l * NA;
#pragma unroll
            for (int q = 0; q < NA / 4; ++q) {
                v4f ov;
                ov.x = o[q * 4 + 0]; ov.y = o[q * 4 + 1];
                ov.z = o[q * 4 + 2]; ov.w = o[q * 4 + 3];
                if (NTOUT) ntstore4(op + q * 4, ov);
                else *(v4f*)(op + q * 4) = ov;
            }
        }
    }
}

// ---------------------------------------------------------------------------
// FUSED agg1 (R1-form, RELU, C=128) + gemm2 (64 out ch) per 64-node block.
// 8 agg iterations (2 nodes/wave) write h1 rows into LDS [64][136] f16;
// one barrier; gemm2 reads A-frags from LDS (h1h never touches HBM).
// Layer-2 aS/aD go to separate buffers (read by agg2 later).
// ---------------------------------------------------------------------------
__global__ __launch_bounds__(256) void agg_gemm_kernel(
    const int* __restrict__ offs, const int* __restrict__ srcs,
    const unsigned* __restrict__ hsrc, const float* __restrict__ aS,
    const float* __restrict__ aD, const float* __restrict__ bias,
    const uint4* __restrict__ Wp2, const float* __restrict__ attS2,
    const float* __restrict__ wda2, unsigned* __restrict__ g2h,
    float* __restrict__ aS2, float* __restrict__ aD2, int n) {
    __shared__ __align__(16) _Float16 lds[64 * 136];
    const int tid = threadIdx.x;
    const int lane = tid & 63;
    const int sl = lane & 31;
    const int hb = lane & 32;
    const int g = (lane >> 4) & 1;
    const int l = lane & 15;
    const int nodeBase = blockIdx.x * 64;

    if (nodeBase + 64 > n) {   // tail block: zero pad rows first
        for (int i = tid; i < 64 * 136 / 2; i += 256) ((unsigned*)lds)[i] = 0u;
        __syncthreads();
    }

    constexpr int LW = 4;   // C=128
    constexpr int NA = 8;

    for (int k = 0; k < 8; ++k) {
        const int node = nodeBase + k * 8 + (tid >> 5);
        if (node < n) {
            const int beg = offs[node], end = offs[node + 1];
            const int deg = end - beg;
            const float ad = aD[node];
            float acc[NA];
#pragma unroll
            for (int i = 0; i < NA; ++i) acc[i] = 0.f;
            int sj = 0;
            float u = 0.f;

            auto ldrow = [&](int s, unsigned* r) {
                uint4 v = ((const uint4*)(hsrc + ((size_t)s << 6)))[l];
                r[0] = v.x; r[1] = v.y; r[2] = v.z; r[3] = v.w;
            };
            auto issue = [&](int j, unsigned (*buf)[LW]) {
                int e0 = hb + j * 8 + g;
                int s0 = __shfl(sj, e0, 64);
                int s1 = __shfl(sj, e0 + 2, 64);
                int s2 = __shfl(sj, e0 + 4, 64);
                int s3 = __shfl(sj, e0 + 6, 64);
                ldrow(s0, buf[0]);
                ldrow(s1, buf[1]);
                ldrow(s2, buf[2]);
                ldrow(s3, buf[3]);
            };
            auto compute = [&](int j, unsigned (*buf)[LW], float inv) {
                int e0 = hb + j * 8 + g;
                float w0 = __shfl(u, e0, 64) * inv, w1 = __shfl(u, e0 + 2, 64) * inv;
                float w2 = __shfl(u, e0 + 4, 64) * inv, w3 = __shfl(u, e0 + 6, 64) * inv;
                v2h w01 = pkrtz(w0, w1);
                v2h w23 = pkrtz(w2, w3);
#pragma unroll
                for (int ii = 0; ii < LW; ++ii) {
                    acc[2 * ii] = fdot2u(__builtin_amdgcn_perm(buf[0][ii], buf[1][ii], SEL_LO), w01,
                                  fdot2u(__builtin_amdgcn_perm(buf[2][ii], buf[3][ii], SEL_LO), w23, acc[2 * ii]));
                    acc[2 * ii + 1] = fdot2u(__builtin_amdgcn_perm(buf[0][ii], buf[1][ii], SEL_HI), w01,
                                     fdot2u(__builtin_amdgcn_perm(buf[2][ii], buf[3][ii], SEL_HI), w23, acc[2 * ii + 1]));
                }
            };

            unsigned A0[4][LW], A1[4][LW];

            if (deg <= 32) {
                int i = beg + sl;
                if (i < end) {
                    sj = __builtin_nontemporal_load(srcs + i);
                    float lg = aS[sj] + ad;
                    lg = (lg > 0.f) ? lg : 0.2f * lg;
                    u = __expf(lg);
                }
                int jm = (deg + 7) >> 3;
                if (jm > 0) issue(0, A0);
                if (jm > 1) issue(1, A1);
                float s = u;
#pragma unroll
                for (int o = 16; o; o >>= 1) s += __shfl_xor(s, o, 64);
                float inv = 1.f / (s + 1e-16f);
                if (jm > 0) { compute(0, A0, inv); if (jm > 2) issue(2, A0); }
                if (jm > 1) { compute(1, A1, inv); if (jm > 3) issue(3, A1); }
                if (jm > 2) compute(2, A0, inv);
                if (jm > 3) compute(3, A1, inv);
            } else {
                float m = -INFINITY;
                for (int i = beg + sl; i < end; i += 32) {
                    float lg = aS[srcs[i]] + ad;
                    lg = (lg > 0.f) ? lg : 0.2f * lg;
                    m = fmaxf(m, lg);
                }
#pragma unroll
                for (int o = 16; o; o >>= 1) m = fmaxf(m, __shfl_xor(m, o, 64));
                float ssum = 0.f;
                for (int i = beg + sl; i < end; i += 32) {
                    float lg = aS[srcs[i]] + ad;
                    lg = (lg > 0.f) ? lg : 0.2f * lg;
                    ssum += __expf(lg - m);
                }
#pragma unroll
                for (int o = 16; o; o >>= 1) ssum += __shfl_xor(ssum, o, 64);
                float inv = 1.f / (ssum + 1e-16f);
                for (int base = beg; base < end; base += 32) {
                    int i = base + sl;
                    sj = 0;
                    u = 0.f;
                    if (i < end) {
                        sj = srcs[i];
                        float lg = aS[sj] + ad;
                        lg = (lg > 0.f) ? lg : 0.2f * lg;
                        u = __expf(lg - m);
                    }
                    int cnt = min(32, end - base);
                    int cj = (cnt + 7) >> 3;
                    if (cj > 0) issue(0, A0);
                    if (cj > 1) issue(1, A1);
                    if (cj > 0) { compute(0, A0, inv); if (cj > 2) issue(2, A0); }
                    if (cj > 1) { compute(1, A1, inv); if (cj > 3) issue(3, A1); }
                    if (cj > 2) compute(2, A0, inv);
                    if (cj > 3) compute(3, A1, inv);
                }
            }

#pragma unroll
            for (int i = 0; i < NA; ++i) acc[i] += __shfl_xor(acc[i], 16, 64);

            if (sl < 16) {
                float o[NA];
                const float* bp = bias + l * NA;
#pragma unroll
                for (int i = 0; i < NA; ++i) o[i] = fmaxf(acc[i] + bp[i], 0.f);  // RELU
                unsigned uo[4];
#pragma unroll
                for (int kk = 0; kk < 4; ++kk) uo[kk] = h2pack(o[2 * kk], o[2 * kk + 1]);
                unsigned* op = (unsigned*)(lds + (size_t)(k * 8 + (tid >> 5)) * 136) + l * 4;
                *(uint4*)op = make_uint4(uo[0], uo[1], uo[2], uo[3]);
            }
        }
    }
    __syncthreads();

    // ---- gemm2: A from LDS rows (stride 136 f16), NT=4 ----
    const int w = tid >> 6;
    const int l15 = lane & 15;
    const int q = lane >> 4;
    const int mb = nodeBase + w * 16;
    const int m = mb + l15;
    const bool mv = m < n;
    const _Float16* xrow = lds + (size_t)(w * 16 + l15) * 136;

    v4f acc2[4];
#pragma unroll
    for (int nn = 0; nn < 4; ++nn) acc2[nn] = (v4f)(0.f);
    float pd = 0.f;
    uint4 afu[4];
#pragma unroll
    for (int t = 0; t < 4; ++t) {
        uint4 u = ((const uint4*)xrow)[4 * t + q];
        afu[t] = u;
        const float* wdp = wda2 + 32 * t + 8 * q;
        pd = fdot2u(u.x, pkrtz(wdp[0], wdp[1]), pd);
        pd = fdot2u(u.y, pkrtz(wdp[2], wdp[3]), pd);
        pd = fdot2u(u.z, pkrtz(wdp[4], wdp[5]), pd);
        pd = fdot2u(u.w, pkrtz(wdp[6], wdp[7]), pd);
    }
#pragma unroll
    for (int t = 0; t < 4; ++t) {
        h8 a = __builtin_bit_cast(h8, afu[t]);
        const uint4* wp = Wp2 + (size_t)t * 4 * 64 + lane;
#pragma unroll
        for (int nn = 0; nn < 4; ++nn) {
            h8 b = __builtin_bit_cast(h8, wp[nn * 64]);
            acc2[nn] = __builtin_amdgcn_mfma_f32_16x16x32_f16(a, b, acc2[nn], 0, 0, 0);
        }
    }

    pd += __shfl_xor(pd, 16, 64);
    pd += __shfl_xor(pd, 32, 64);
    if (q == 0 && mv) aD2[m] = pd;

    float as4[4] = {0.f, 0.f, 0.f, 0.f};
#pragma unroll
    for (int nn = 0; nn < 4; ++nn) {
        float av = attS2[nn * 16 + l15];
#pragma unroll
        for (int r = 0; r < 4; ++r) as4[r] += acc2[nn][r] * av;
    }
#pragma unroll
    for (int r = 0; r < 4; ++r) {
#pragma unroll
        for (int o = 1; o < 16; o <<= 1) as4[r] += __shfl_xor(as4[r], o, 64);
    }
    if (l15 == 0) {
#pragma unroll
        for (int r = 0; r < 4; ++r) {
            int row = mb + q * 4 + r;
            if (row < n) aS2[row] = as4[r];
        }
    }

    // transpose into this wave's own quarter (rows already consumed; wave-local)
    _Float16* hp = lds + (size_t)w * (16 * 136);
#pragma unroll
    for (int nn = 0; nn < 4; ++nn)
#pragma unroll
        for (int r = 0; r < 4; ++r)
            hp[(q * 4 + r) * 136 + nn * 16 + l15] = (_Float16)acc2[nn][r];

    if (lane < 32) {   // CH=2: 16 rows x 2 chunks of 64 B
        int row = lane >> 1;
        int ch = lane & 1;
        const uint4* rp = (const uint4*)(hp + row * 136 + ch * 32);
        uint4 v0 = rp[0], v1 = rp[1], v2 = rp[2], v3 = rp[3];
        int gr = mb + row;
        if (gr < n) {
            uint4* op = (uint4*)(g2h + (size_t)gr * 32) + ch * 4;
            op[0] = v0; op[1] = v1; op[2] = v2; op[3] = v3;
        }
    }
}

extern "C" void kernel_launch(void* const* d_in, const int* in_sizes, int n_in,
                              void* d_out, int out_size, void* d_ws, size_t ws_size,
                              hipStream_t stream) {
    const float* x     = (const float*)d_in[0];
    const int*   edge  = (const int*)d_in[1];
    const float* W1s   = (const float*)d_in[2];
    const float* W1d   = (const float*)d_in[3];
    const float* att1s = (const float*)d_in[4];
    const float* att1d = (const float*)d_in[5];
    const float* b1    = (const float*)d_in[6];
    const float* W2s   = (const float*)d_in[7];
    const float* W2d   = (const float*)d_in[8];
    const float* att2s = (const float*)d_in[9];
    const float* att2d = (const float*)d_in[10];
    const float* b2    = (const float*)d_in[11];

    const int N = in_sizes[0] / 128;
    const int E = in_sizes[1] / 2;
    const int* srcI = edge;
    const int* dstI = edge + E;

    const int nbE = (E + 4095) / 4096;
    const int nbuckets = (N + 511) >> 9;
    const int gblk = (N + 63) / 64;

    size_t off = 0;
    auto alloc = [&](size_t bytes) {
        void* p = (char*)d_ws + off;
        off += (bytes + 255) & ~(size_t)255;
        return p;
    };
    int*      offs  = (int*)alloc((size_t)(N + 1) * 4);
    int*      srcs  = (int*)alloc((size_t)E * 4);
    int*      hist  = (int*)alloc((size_t)nbE * 256 * 4);
    int*      bbase = (int*)alloc(257 * 4);
    int*      gcur  = (int*)alloc(256 * 4);
    float*    watt1 = (float*)alloc(128 * 4);
    float*    watt2 = (float*)alloc(128 * 4);
    uint4*    wp1   = (uint4*)alloc(4 * 8 * 64 * 16);        // packed W1s f16
    uint4*    wp2   = (uint4*)alloc(4 * 4 * 64 * 16);        // packed W2s f16
    float*    a_s   = (float*)alloc((size_t)N * 4);
    float*    a_d   = (float*)alloc((size_t)N * 4);
    float*    a_s2  = (float*)alloc((size_t)N * 4);
    float*    a_d2  = (float*)alloc((size_t)N * 4);
    unsigned* g1h   = (unsigned*)alloc((size_t)N * 128 * 2); // gemm1 out (gather), f16
    unsigned* g2h   = (unsigned*)alloc((size_t)N * 64 * 2);  // gemm2 out (gather), f16
    u64*      pairs = (u64*)g2h;   // dead until agg_gemm writes g2h (bsort << agg_gemm)

    setup_kernel<<<nbE + 66, 256, 0, stream>>>(dstI, hist, E, nbE, W1s, wp1, W2s, wp2,
                                               W1d, att1d, watt1, W2d, att2d, watt2);
    bscan_kernel<<<1, 256, 0, stream>>>(hist, nbE, bbase, gcur, offs, N, E);
    scatter_gemm_kernel<<<nbE + gblk, 256, 0, stream>>>(srcI, dstI, gcur, pairs, E, nbE,
                                                        x, wp1, att1s, watt1, g1h, a_s, a_d, N);
    bsort_kernel<<<nbuckets, 512, 0, stream>>>(pairs, bbase, offs, srcs, N);
    agg_gemm_kernel<<<gblk, 256, 0, stream>>>(offs, srcs, g1h, a_s, a_d, b1,
                                              wp2, att2s, watt2, g2h, a_s2, a_d2, N);
    aggregate_kernel<64, false, false, true><<<(N + 7) / 8, 256, 0, stream>>>(
        offs, srcs, g2h, a_s2, a_d2, b2, d_out, N);
}

// Round 6
// 284.762 us; speedup vs baseline: 1.1285x; 1.1285x over previous
//
#include <hip/hip_runtime.h>

// ---------------------------------------------------------------------------
// GAT 2-layer encoder. N=100k nodes, E=1.6M edges, 128->128(relu)->64.
//   a_dst = x . (W_dst @ att_dst)  (h_dst never materialized)
//   CSR-by-dst via two-level counting sort, u32-packed pairs (9b local | 17b src)
//   MFMA f16 GEMM (16x16x32), W pre-packed to fragment layout, fused aS/aD
//   aggregation: R1 form — 2 nodes/wave, aS gather first, double-buffered
//   agg1+gemm2 fused per 64-node block, 512 threads (4 iters x 16 nodes ->
//   2x resident waves vs R5); h1 rows stay in LDS. 7 dispatches (incl memset).
// ---------------------------------------------------------------------------

typedef unsigned long long u64;
typedef float v4f __attribute__((ext_vector_type(4)));
typedef _Float16 v2h __attribute__((ext_vector_type(2)));
typedef __fp16 h8 __attribute__((ext_vector_type(8)));

#define SEL_LO 0x01000504u   // (a.f16lo, b.f16lo)
#define SEL_HI 0x03020706u   // (a.f16hi, b.f16hi)

__device__ __forceinline__ void ntstore4(float* p, v4f v) {
    __builtin_nontemporal_store(v, (v4f*)p);
}
__device__ __forceinline__ unsigned h2pack(float a, float b) {  // RNE
    v2h h;
    h.x = (_Float16)a;
    h.y = (_Float16)b;
    return __builtin_bit_cast(unsigned, h);
}
__device__ __forceinline__ float fdot2u(unsigned u, v2h w, float acc) {
    return __builtin_amdgcn_fdot2(__builtin_bit_cast(v2h, u), w, acc, false);
}
__device__ __forceinline__ v2h pkrtz(float a, float b) {
    return __builtin_bit_cast(v2h, __builtin_amdgcn_cvt_pkrtz(a, b));
}

// ---- fused setup: dst histogram (global atomics) + W packing + matvecs ----
__device__ void matvec_body(const float* __restrict__ W, const float* __restrict__ a,
                            float* __restrict__ out, int cols, int row) {
    int lane = threadIdx.x & 63;
    float s = 0.f;
    for (int j = lane; j < cols; j += 64) s += W[row * cols + j] * a[j];
#pragma unroll
    for (int o = 32; o; o >>= 1) s += __shfl_xor(s, o, 64);
    if (lane == 0) out[row] = s;
}

// pack W [128 x C] f32 -> MFMA B-fragment order, f16:
//   Wp[(t*NT + tile)*64 + lane] = 8 f16 { W[32t+(lane>>4)*8+j][tile*16+(lane&15)] }
template <int C>
__device__ void packw_body(const float* __restrict__ W, uint4* __restrict__ Wp) {
    constexpr int NT = C / 16;
    const int total = 4 * NT * 64;
    for (int e = threadIdx.x; e < total; e += 256) {
        int lane = e & 63;
        int ti = (e >> 6) % NT;
        int t = (e >> 6) / NT;
        int k0 = 32 * t + (lane >> 4) * 8;
        int n = ti * 16 + (lane & 15);
        unsigned u[4];
#pragma unroll
        for (int p = 0; p < 4; ++p)
            u[p] = h2pack(W[(size_t)(k0 + 2 * p) * C + n], W[(size_t)(k0 + 2 * p + 1) * C + n]);
        Wp[e] = make_uint4(u[0], u[1], u[2], u[3]);
    }
}

__global__ __launch_bounds__(256) void setup_kernel(
    const int* __restrict__ dst, int* __restrict__ gh, int E, int nbE,
    const float* __restrict__ W1s, uint4* __restrict__ wp1,
    const float* __restrict__ W2s, uint4* __restrict__ wp2,
    const float* __restrict__ W1d, const float* __restrict__ att1d, float* __restrict__ watt1,
    const float* __restrict__ W2d, const float* __restrict__ att2d, float* __restrict__ watt2) {
    int b = blockIdx.x;
    if (b < nbE) {
        __shared__ int h[256];
        h[threadIdx.x] = 0;
        __syncthreads();
        int base = b * 4096;
        int lim = min(base + 4096, E);
        for (int i = base + threadIdx.x; i < lim; i += 256)
            atomicAdd(&h[__builtin_nontemporal_load(dst + i) >> 9], 1);
        __syncthreads();
        int v = h[threadIdx.x];
        if (v) atomicAdd(&gh[threadIdx.x], v);
    } else if (b == nbE) {
        packw_body<128>(W1s, wp1);
    } else if (b == nbE + 1) {
        packw_body<64>(W2s, wp2);
    } else if (b < nbE + 34) {
        matvec_body(W1d, att1d, watt1, 128, (b - nbE - 2) * 4 + (threadIdx.x >> 6));
    } else {
        matvec_body(W2d, att2d, watt2, 64, (b - nbE - 34) * 4 + (threadIdx.x >> 6));
    }
}

__global__ __launch_bounds__(256) void bscan_kernel(const int* __restrict__ gh,
                                                    int* __restrict__ bbase,
                                                    int* __restrict__ gcur,
                                                    int* __restrict__ offs, int N, int E) {
    __shared__ int s[256];
    int t = threadIdx.x;
    int v = gh[t];
    s[t] = v;
    __syncthreads();
    for (int o = 1; o < 256; o <<= 1) {
        int u = (t >= o) ? s[t - o] : 0;
        __syncthreads();
        s[t] += u;
        __syncthreads();
    }
    int excl = s[t] - v;
    bbase[t] = excl;
    gcur[t] = excl;
    if (t == 255) { bbase[256] = E; offs[N] = E; }
}

// rank within block, stage u32 pairs in LDS in bucket order, write coalesced
__device__ void scatter_body(const int* __restrict__ src, const int* __restrict__ dst,
                             int* __restrict__ gcur, unsigned* __restrict__ pairs, int E,
                             int blk, char* smem) {
    int* h = (int*)smem;                                   // 1024 B
    int* sbase = h + 256;                                  // 1024 B
    int* rbase = h + 512;                                  // 1024 B
    unsigned* buf = (unsigned*)(smem + 3072);              // 16384 B
    unsigned char* b8 = (unsigned char*)(smem + 19456);    // 4096 B
    const int tid = threadIdx.x;
    h[tid] = 0;
    __syncthreads();
    const int base = blk * 4096;
    const int lim = min(4096, E - base);
    unsigned pv[16];
    int rk[16];
    int bk[16];
#pragma unroll 16
    for (int k = 0; k < 16; ++k) {
        int i = base + k * 256 + tid;
        if (i < E) {
            int d = __builtin_nontemporal_load(dst + i);
            int b = d >> 9;
            bk[k] = b;
            pv[k] = ((unsigned)(d & 511) << 17) |
                    (unsigned)__builtin_nontemporal_load(src + i);
            rk[k] = atomicAdd(&h[b], 1);
        } else {
            bk[k] = -1;
        }
    }
    __syncthreads();
    const int v = h[tid];
    sbase[tid] = v;
    __syncthreads();
    for (int o = 1; o < 256; o <<= 1) {
        int uu = (tid >= o) ? sbase[tid - o] : 0;
        __syncthreads();
        sbase[tid] += uu;
        __syncthreads();
    }
    const int excl = sbase[tid] - v;
    rbase[tid] = v ? atomicAdd(&gcur[tid], v) : 0;
    __syncthreads();
    sbase[tid] = excl;
    __syncthreads();
#pragma unroll 16
    for (int k = 0; k < 16; ++k)
        if (bk[k] >= 0) {
            int pos = sbase[bk[k]] + rk[k];
            buf[pos] = pv[k];
            b8[pos] = (unsigned char)bk[k];
        }
    __syncthreads();
    for (int i = tid; i < lim; i += 256) {
        unsigned p = buf[i];
        int b = b8[i];
        __builtin_nontemporal_store(p, pairs + (size_t)rbase[b] + (i - sbase[b]));
    }
}

__global__ __launch_bounds__(512) void bsort_kernel(const unsigned* __restrict__ pairs,
                                                    const int* __restrict__ bbase,
                                                    int* __restrict__ offs,
                                                    int* __restrict__ srcs, int N) {
    __shared__ int h[512];
    __shared__ int cur[512];
    const int t = threadIdx.x;
    const int b = blockIdx.x;
    const int beg = bbase[b], end = bbase[b + 1];
    h[t] = 0;
    __syncthreads();
    for (int i = beg + t; i < end; i += 512)
        atomicAdd(&h[__builtin_nontemporal_load(pairs + i) >> 17], 1);
    __syncthreads();
    int v = h[t];
    cur[t] = v;
    __syncthreads();
    for (int o = 1; o < 512; o <<= 1) {
        int u = (t >= o) ? cur[t - o] : 0;
        __syncthreads();
        cur[t] += u;
        __syncthreads();
    }
    int pos0 = beg + cur[t] - v;
    __syncthreads();
    cur[t] = pos0;
    int g = (b << 9) + t;
    if (g < N) offs[g] = pos0;
    __syncthreads();
    for (int i = beg + t; i < end; i += 512) {
        unsigned p = __builtin_nontemporal_load(pairs + i);
        int local = (int)(p >> 17);
        int pp = atomicAdd(&cur[local], 1);
        srcs[pp] = (int)(p & 0x1FFFFu);
    }
}

// MFMA GEMM: H[M,C] (f16) = X[M,128] @ W; fused aS = H.attS, aD = X.wda.
// Layouts (m89-verified): A[m=lane&15][k=quad*8+j]; B[k=quad*8+j][n=lane&15];
// D col=lane&15, row=quad*4+reg.
template <int C, bool XF16>
__device__ void gemm_body(int blk, const void* __restrict__ Xv, const uint4* __restrict__ Wp,
                          const float* __restrict__ attS, const float* __restrict__ wda,
                          unsigned* __restrict__ H, float* __restrict__ aS,
                          float* __restrict__ aD, int M, _Float16* hsAll) {
    constexpr int NT = C / 16;
    const int tid = threadIdx.x;
    const int w = tid >> 6;
    const int lane = tid & 63;
    const int l15 = lane & 15;
    const int q = lane >> 4;
    const int mb = blk * 64 + w * 16;
    const int m = mb + l15;
    const bool mv = m < M;

    v4f acc[NT];
#pragma unroll
    for (int n = 0; n < NT; ++n) acc[n] = (v4f)(0.f);
    float pd = 0.f;
    uint4 afu[4];

    if constexpr (XF16) {
        const uint4* Xp = (const uint4*)Xv + (size_t)m * 16;   // 128 f16 = 16 uint4
#pragma unroll
        for (int t = 0; t < 4; ++t) {
            uint4 u = make_uint4(0u, 0u, 0u, 0u);
            if (mv) u = Xp[4 * t + q];
            afu[t] = u;
            const float* wdp = wda + 32 * t + 8 * q;
            pd = fdot2u(u.x, pkrtz(wdp[0], wdp[1]), pd);
            pd = fdot2u(u.y, pkrtz(wdp[2], wdp[3]), pd);
            pd = fdot2u(u.z, pkrtz(wdp[4], wdp[5]), pd);
            pd = fdot2u(u.w, pkrtz(wdp[6], wdp[7]), pd);
        }
    } else {
        const float* Xp = (const float*)Xv + (size_t)m * 128;
#pragma unroll
        for (int t = 0; t < 4; ++t) {
            float4 x0 = make_float4(0.f, 0.f, 0.f, 0.f);
            float4 x1 = x0;
            if (mv) {
                x0 = *(const float4*)(Xp + 32 * t + 8 * q);
                x1 = *(const float4*)(Xp + 32 * t + 8 * q + 4);
            }
            const float* wdp = wda + 32 * t + 8 * q;
            pd += x0.x * wdp[0] + x0.y * wdp[1] + x0.z * wdp[2] + x0.w * wdp[3] +
                  x1.x * wdp[4] + x1.y * wdp[5] + x1.z * wdp[6] + x1.w * wdp[7];
            afu[t] = make_uint4(h2pack(x0.x, x0.y), h2pack(x0.z, x0.w),
                                h2pack(x1.x, x1.y), h2pack(x1.z, x1.w));
        }
    }

    // MFMA main loop
#pragma unroll
    for (int t = 0; t < 4; ++t) {
        h8 a = __builtin_bit_cast(h8, afu[t]);
        const uint4* wp = Wp + (size_t)t * NT * 64 + lane;
#pragma unroll
        for (int n = 0; n < NT; ++n) {
            h8 b = __builtin_bit_cast(h8, wp[n * 64]);
            acc[n] = __builtin_amdgcn_mfma_f32_16x16x32_f16(a, b, acc[n], 0, 0, 0);
        }
    }

    // aD: reduce per-lane partial over quads (lanes sharing m)
    pd += __shfl_xor(pd, 16, 64);
    pd += __shfl_xor(pd, 32, 64);
    if (q == 0 && mv) aD[m] = pd;

    // aS: dot accumulators with attS, reduce across the 16 cols (same quad)
    float as4[4] = {0.f, 0.f, 0.f, 0.f};
#pragma unroll
    for (int n = 0; n < NT; ++n) {
        float av = attS[n * 16 + l15];
#pragma unroll
        for (int r = 0; r < 4; ++r) as4[r] += acc[n][r] * av;
    }
#pragma unroll
    for (int r = 0; r < 4; ++r) {
#pragma unroll
        for (int o = 1; o < 16; o <<= 1) as4[r] += __shfl_xor(as4[r], o, 64);
    }
    if (l15 == 0) {
#pragma unroll
        for (int r = 0; r < 4; ++r) {
            int row = mb + q * 4 + r;
            if (row < M) aS[row] = as4[r];
        }
    }

    // H store: f16 via per-wave LDS transpose (wave-local; no barrier needed)
    _Float16* hp = hsAll + w * (16 * 136);
#pragma unroll
    for (int n = 0; n < NT; ++n)
#pragma unroll
        for (int r = 0; r < 4; ++r)
            hp[(q * 4 + r) * 136 + n * 16 + l15] = (_Float16)acc[n][r];

    constexpr int CH = C / 32;              // 64-B chunks per row
    if (lane < 16 * CH) {
        int row = lane / CH;
        int ch = lane % CH;
        const uint4* rp = (const uint4*)(hp + row * 136 + ch * 32);
        uint4 v0 = rp[0], v1 = rp[1], v2 = rp[2], v3 = rp[3];
        int gr = mb + row;
        if (gr < M) {
            uint4* op = (uint4*)(H + (size_t)gr * (C / 2)) + ch * 4;
            op[0] = v0; op[1] = v1; op[2] = v2; op[3] = v3;
        }
    }
}

// fused: bscatter blocks [0,nbS) | gemm1 blocks [nbS, nbS+gblk)
__global__ __launch_bounds__(256) void scatter_gemm_kernel(
    const int* __restrict__ src, const int* __restrict__ dst, int* __restrict__ gcur,
    unsigned* __restrict__ pairs, int E, int nbS,
    const void* __restrict__ Xv, const uint4* __restrict__ Wp,
    const float* __restrict__ attS, const float* __restrict__ wda,
    unsigned* __restrict__ H, float* __restrict__ aS, float* __restrict__ aD, int M) {
    __shared__ __align__(16) char smem[23552];
    int b = blockIdx.x;
    if (b < nbS) scatter_body(src, dst, gcur, pairs, E, b, smem);
    else gemm_body<128, false>(b - nbS, Xv, Wp, attS, wda, H, aS, aD, M, (_Float16*)smem);
}

// Segment softmax + weighted aggregation (R1 form, standalone — used for agg2).
template <int C, bool RELU, bool F16OUT, bool NTOUT>
__global__ __launch_bounds__(256) void aggregate_kernel(
    const int* __restrict__ offs, const int* __restrict__ srcs,
    const unsigned* __restrict__ hsrc, const float* __restrict__ aS,
    const float* __restrict__ aD, const float* __restrict__ bias,
    void* __restrict__ outv, int n) {
    const int lane = threadIdx.x & 63;
    const int sl = lane & 31;            // slot within half
    const int hb = lane & 32;            // half base (0 or 32) for shuffles
    const int g = (lane >> 4) & 1;       // group within half
    const int l = lane & 15;
    int node = (int)((blockIdx.x * blockDim.x + threadIdx.x) >> 5);  // 2 nodes/wave
    if (node >= n) return;

    const int beg = offs[node], end = offs[node + 1];
    const int deg = end - beg;
    const float ad = aD[node];

    constexpr int LW = C / 32;           // dwords per lane per gathered row
    constexpr int NA = C / 16;           // f32 accumulators per lane
    float acc[NA];
#pragma unroll
    for (int i = 0; i < NA; ++i) acc[i] = 0.f;

    int sj = 0;
    float u = 0.f;

    auto ldrow = [&](int s, unsigned* r) {
        if constexpr (C == 128) {
            uint4 v = ((const uint4*)(hsrc + ((size_t)s << 6)))[l];
            r[0] = v.x; r[1] = v.y; r[2] = v.z; r[3] = v.w;
        } else {
            uint2 v = ((const uint2*)(hsrc + ((size_t)s << 5)))[l];
            r[0] = v.x; r[1] = v.y;
        }
    };
    auto issue = [&](int j, unsigned (*buf)[LW]) {
        int e0 = hb + j * 8 + g;
        int s0 = __shfl(sj, e0, 64);
        int s1 = __shfl(sj, e0 + 2, 64);
        int s2 = __shfl(sj, e0 + 4, 64);
        int s3 = __shfl(sj, e0 + 6, 64);
        ldrow(s0, buf[0]);
        ldrow(s1, buf[1]);
        ldrow(s2, buf[2]);
        ldrow(s3, buf[3]);
    };
    auto compute = [&](int j, unsigned (*buf)[LW], float inv) {
        int e0 = hb + j * 8 + g;
        float w0 = __shfl(u, e0, 64) * inv, w1 = __shfl(u, e0 + 2, 64) * inv;
        float w2 = __shfl(u, e0 + 4, 64) * inv, w3 = __shfl(u, e0 + 6, 64) * inv;
        v2h w01 = pkrtz(w0, w1);
        v2h w23 = pkrtz(w2, w3);
#pragma unroll
        for (int ii = 0; ii < LW; ++ii) {
            acc[2 * ii] = fdot2u(__builtin_amdgcn_perm(buf[0][ii], buf[1][ii], SEL_LO), w01,
                          fdot2u(__builtin_amdgcn_perm(buf[2][ii], buf[3][ii], SEL_LO), w23, acc[2 * ii]));
            acc[2 * ii + 1] = fdot2u(__builtin_amdgcn_perm(buf[0][ii], buf[1][ii], SEL_HI), w01,
                              fdot2u(__builtin_amdgcn_perm(buf[2][ii], buf[3][ii], SEL_HI), w23, acc[2 * ii + 1]));
        }
    };

    unsigned A0[4][LW], A1[4][LW];

    if (deg <= 32) {
        int i = beg + sl;
        if (i < end) {
            sj = __builtin_nontemporal_load(srcs + i);
            float lg = aS[sj] + ad;
            lg = (lg > 0.f) ? lg : 0.2f * lg;
            u = __expf(lg);
        }
        int jm = (deg + 7) >> 3;
        if (jm > 0) issue(0, A0);
        if (jm > 1) issue(1, A1);
        float s = u;
#pragma unroll
        for (int o = 16; o; o >>= 1) s += __shfl_xor(s, o, 64);
        float inv = 1.f / (s + 1e-16f);
        if (jm > 0) { compute(0, A0, inv); if (jm > 2) issue(2, A0); }
        if (jm > 1) { compute(1, A1, inv); if (jm > 3) issue(3, A1); }
        if (jm > 2) compute(2, A0, inv);
        if (jm > 3) compute(3, A1, inv);
    } else {
        float m = -INFINITY;
        for (int i = beg + sl; i < end; i += 32) {
            float lg = aS[srcs[i]] + ad;
            lg = (lg > 0.f) ? lg : 0.2f * lg;
            m = fmaxf(m, lg);
        }
#pragma unroll
        for (int o = 16; o; o >>= 1) m = fmaxf(m, __shfl_xor(m, o, 64));
        float ssum = 0.f;
        for (int i = beg + sl; i < end; i += 32) {
            float lg = aS[srcs[i]] + ad;
            lg = (lg > 0.f) ? lg : 0.2f * lg;
            ssum += __expf(lg - m);
        }
#pragma unroll
        for (int o = 16; o; o >>= 1) ssum += __shfl_xor(ssum, o, 64);
        float inv = 1.f / (ssum + 1e-16f);
        for (int base = beg; base < end; base += 32) {
            int i = base + sl;
            sj = 0;
            u = 0.f;
            if (i < end) {
                sj = srcs[i];
                float lg = aS[sj] + ad;
                lg = (lg > 0.f) ? lg : 0.2f * lg;
                u = __expf(lg - m);
            }
            int cnt = min(32, end - base);
            int cj = (cnt + 7) >> 3;
            if (cj > 0) issue(0, A0);
            if (cj > 1) issue(1, A1);
            if (cj > 0) { compute(0, A0, inv); if (cj > 2) issue(2, A0); }
            if (cj > 1) { compute(1, A1, inv); if (cj > 3) issue(3, A1); }
            if (cj > 2) compute(2, A0, inv);
            if (cj > 3) compute(3, A1, inv);
        }
    }

#pragma unroll
    for (int i = 0; i < NA; ++i) acc[i] += __shfl_xor(acc[i], 16, 64);

    if (sl < 16) {
        float o[NA];
        const float* bp = bias + l * NA;
#pragma unroll
        for (int i = 0; i < NA; ++i) {
            o[i] = acc[i] + bp[i];
            if (RELU) o[i] = fmaxf(o[i], 0.f);
        }
        if constexpr (F16OUT) {
            unsigned uo[NA / 2];
#pragma unroll
            for (int k = 0; k < NA / 2; ++k) uo[k] = h2pack(o[2 * k], o[2 * k + 1]);
            unsigned* op = (unsigned*)outv + (size_t)node * (C / 2) + l * (NA / 2);
            if constexpr (NA == 8) *(uint4*)op = make_uint4(uo[0], uo[1], uo[2], uo[3]);
            else *(uint2*)op = make_uint2(uo[0], uo[1]);
        } else {
            float* op = (float*)outv + (size_t)node * C + l * NA;
#pragma unroll
            for (int q = 0; q < NA / 4; ++q) {
                v4f ov;
                ov.x = o[q * 4 + 0]; ov.y = o[q * 4 + 1];
                ov.z = o[q * 4 + 2]; ov.w = o[q * 4 + 3];
                if (NTOUT) ntstore4(op + q * 4, ov);
                else *(v4f*)(op + q * 4) = ov;
            }
        }
    }
}

// ---------------------------------------------------------------------------
// FUSED agg1 (R1-form, RELU, C=128) + gemm2 (64 out ch) per 64-node block.
// 512 threads: 4 agg iterations x 16 nodes (16 half-waves) -> 2x resident
// waves vs the 256-thread R5 version. One barrier; gemm2 on waves 0-3.
// ---------------------------------------------------------------------------
__global__ __launch_bounds__(512) void agg_gemm_kernel(
    const int* __restrict__ offs, const int* __restrict__ srcs,
    const unsigned* __restrict__ hsrc, const float* __restrict__ aS,
    const float* __restrict__ aD, const float* __restrict__ bias,
    const uint4* __restrict__ Wp2, const float* __restrict__ attS2,
    const float* __restrict__ wda2, unsigned* __restrict__ g2h,
    float* __restrict__ aS2, float* __restrict__ aD2, int n) {
    __shared__ __align__(16) _Float16 lds[64 * 136];
    const int tid = threadIdx.x;
    const int lane = tid & 63;
    const int sl = lane & 31;
    const int hb = lane & 32;
    const int g = (lane >> 4) & 1;
    const int l = lane & 15;
    const int nodeBase = blockIdx.x * 64;

    if (nodeBase + 64 > n) {   // tail block: zero pad rows first
        for (int i = tid; i < 64 * 136 / 2; i += 512) ((unsigned*)lds)[i] = 0u;
        __syncthreads();
    }

    constexpr int LW = 4;   // C=128
    constexpr int NA = 8;

    for (int k = 0; k < 4; ++k) {
        const int row = k * 16 + (tid >> 5);
        const int node = nodeBase + row;
        if (node < n) {
            const int beg = offs[node], end = offs[node + 1];
            const int deg = end - beg;
            const float ad = aD[node];
            float acc[NA];
#pragma unroll
            for (int i = 0; i < NA; ++i) acc[i] = 0.f;
            int sj = 0;
            float u = 0.f;

            auto ldrow = [&](int s, unsigned* r) {
                uint4 v = ((const uint4*)(hsrc + ((size_t)s << 6)))[l];
                r[0] = v.x; r[1] = v.y; r[2] = v.z; r[3] = v.w;
            };
            auto issue = [&](int j, unsigned (*buf)[LW]) {
                int e0 = hb + j * 8 + g;
                int s0 = __shfl(sj, e0, 64);
                int s1 = __shfl(sj, e0 + 2, 64);
                int s2 = __shfl(sj, e0 + 4, 64);
                int s3 = __shfl(sj, e0 + 6, 64);
                ldrow(s0, buf[0]);
                ldrow(s1, buf[1]);
                ldrow(s2, buf[2]);
                ldrow(s3, buf[3]);
            };
            auto compute = [&](int j, unsigned (*buf)[LW], float inv) {
                int e0 = hb + j * 8 + g;
                float w0 = __shfl(u, e0, 64) * inv, w1 = __shfl(u, e0 + 2, 64) * inv;
                float w2 = __shfl(u, e0 + 4, 64) * inv, w3 = __shfl(u, e0 + 6, 64) * inv;
                v2h w01 = pkrtz(w0, w1);
                v2h w23 = pkrtz(w2, w3);
#pragma unroll
                for (int ii = 0; ii < LW; ++ii) {
                    acc[2 * ii] = fdot2u(__builtin_amdgcn_perm(buf[0][ii], buf[1][ii], SEL_LO), w01,
                                  fdot2u(__builtin_amdgcn_perm(buf[2][ii], buf[3][ii], SEL_LO), w23, acc[2 * ii]));
                    acc[2 * ii + 1] = fdot2u(__builtin_amdgcn_perm(buf[0][ii], buf[1][ii], SEL_HI), w01,
                                     fdot2u(__builtin_amdgcn_perm(buf[2][ii], buf[3][ii], SEL_HI), w23, acc[2 * ii + 1]));
                }
            };

            unsigned A0[4][LW], A1[4][LW];

            if (deg <= 32) {
                int i = beg + sl;
                if (i < end) {
                    sj = __builtin_nontemporal_load(srcs + i);
                    float lg = aS[sj] + ad;
                    lg = (lg > 0.f) ? lg : 0.2f * lg;
                    u = __expf(lg);
                }
                int jm = (deg + 7) >> 3;
                if (jm > 0) issue(0, A0);
                if (jm > 1) issue(1, A1);
                float s = u;
#pragma unroll
                for (int o = 16; o; o >>= 1) s += __shfl_xor(s, o, 64);
                float inv = 1.f / (s + 1e-16f);
                if (jm > 0) { compute(0, A0, inv); if (jm > 2) issue(2, A0); }
                if (jm > 1) { compute(1, A1, inv); if (jm > 3) issue(3, A1); }
                if (jm > 2) compute(2, A0, inv);
                if (jm > 3) compute(3, A1, inv);
            } else {
                float m = -INFINITY;
                for (int i = beg + sl; i < end; i += 32) {
                    float lg = aS[srcs[i]] + ad;
                    lg = (lg > 0.f) ? lg : 0.2f * lg;
                    m = fmaxf(m, lg);
                }
#pragma unroll
                for (int o = 16; o; o >>= 1) m = fmaxf(m, __shfl_xor(m, o, 64));
                float ssum = 0.f;
                for (int i = beg + sl; i < end; i += 32) {
                    float lg = aS[srcs[i]] + ad;
                    lg = (lg > 0.f) ? lg : 0.2f * lg;
                    ssum += __expf(lg - m);
                }
#pragma unroll
                for (int o = 16; o; o >>= 1) ssum += __shfl_xor(ssum, o, 64);
                float inv = 1.f / (ssum + 1e-16f);
                for (int base = beg; base < end; base += 32) {
                    int i = base + sl;
                    sj = 0;
                    u = 0.f;
                    if (i < end) {
                        sj = srcs[i];
                        float lg = aS[sj] + ad;
                        lg = (lg > 0.f) ? lg : 0.2f * lg;
                        u = __expf(lg - m);
                    }
                    int cnt = min(32, end - base);
                    int cj = (cnt + 7) >> 3;
                    if (cj > 0) issue(0, A0);
                    if (cj > 1) issue(1, A1);
                    if (cj > 0) { compute(0, A0, inv); if (cj > 2) issue(2, A0); }
                    if (cj > 1) { compute(1, A1, inv); if (cj > 3) issue(3, A1); }
                    if (cj > 2) compute(2, A0, inv);
                    if (cj > 3) compute(3, A1, inv);
                }
            }

#pragma unroll
            for (int i = 0; i < NA; ++i) acc[i] += __shfl_xor(acc[i], 16, 64);

            if (sl < 16) {
                float o[NA];
                const float* bp = bias + l * NA;
#pragma unroll
                for (int i = 0; i < NA; ++i) o[i] = fmaxf(acc[i] + bp[i], 0.f);  // RELU
                unsigned uo[4];
#pragma unroll
                for (int kk = 0; kk < 4; ++kk) uo[kk] = h2pack(o[2 * kk], o[2 * kk + 1]);
                unsigned* op = (unsigned*)(lds + (size_t)row * 136) + l * 4;
                *(uint4*)op = make_uint4(uo[0], uo[1], uo[2], uo[3]);
            }
        }
    }
    __syncthreads();

    // ---- gemm2 on waves 0-3: A from LDS rows (stride 136 f16), NT=4 ----
    const int w = tid >> 6;
    if (w >= 4) return;
    const int l15 = lane & 15;
    const int q = lane >> 4;
    const int mb = nodeBase + w * 16;
    const int m = mb + l15;
    const bool mv = m < n;
    const _Float16* xrow = lds + (size_t)(w * 16 + l15) * 136;

    v4f acc2[4];
#pragma unroll
    for (int nn = 0; nn < 4; ++nn) acc2[nn] = (v4f)(0.f);
    float pd = 0.f;
    uint4 afu[4];
#pragma unroll
    for (int t = 0; t < 4; ++t) {
        uint4 u = ((const uint4*)xrow)[4 * t + q];
        afu[t] = u;
        const float* wdp = wda2 + 32 * t + 8 * q;
        pd = fdot2u(u.x, pkrtz(wdp[0], wdp[1]), pd);
        pd = fdot2u(u.y, pkrtz(wdp[2], wdp[3]), pd);
        pd = fdot2u(u.z, pkrtz(wdp[4], wdp[5]), pd);
        pd = fdot2u(u.w, pkrtz(wdp[6], wdp[7]), pd);
    }
#pragma unroll
    for (int t = 0; t < 4; ++t) {
        h8 a = __builtin_bit_cast(h8, afu[t]);
        const uint4* wp = Wp2 + (size_t)t * 4 * 64 + lane;
#pragma unroll
        for (int nn = 0; nn < 4; ++nn) {
            h8 b = __builtin_bit_cast(h8, wp[nn * 64]);
            acc2[nn] = __builtin_amdgcn_mfma_f32_16x16x32_f16(a, b, acc2[nn], 0, 0, 0);
        }
    }

    pd += __shfl_xor(pd, 16, 64);
    pd += __shfl_xor(pd, 32, 64);
    if (q == 0 && mv) aD2[m] = pd;

    float as4[4] = {0.f, 0.f, 0.f, 0.f};
#pragma unroll
    for (int nn = 0; nn < 4; ++nn) {
        float av = attS2[nn * 16 + l15];
#pragma unroll
        for (int r = 0; r < 4; ++r) as4[r] += acc2[nn][r] * av;
    }
#pragma unroll
    for (int r = 0; r < 4; ++r) {
#pragma unroll
        for (int o = 1; o < 16; o <<= 1) as4[r] += __shfl_xor(as4[r], o, 64);
    }
    if (l15 == 0) {
#pragma unroll
        for (int r = 0; r < 4; ++r) {
            int row = mb + q * 4 + r;
            if (row < n) aS2[row] = as4[r];
        }
    }

    // transpose into this wave's own quarter (rows already consumed; wave-local)
    _Float16* hp = lds + (size_t)w * (16 * 136);
#pragma unroll
    for (int nn = 0; nn < 4; ++nn)
#pragma unroll
        for (int r = 0; r < 4; ++r)
            hp[(q * 4 + r) * 136 + nn * 16 + l15] = (_Float16)acc2[nn][r];

    if (lane < 32) {   // CH=2: 16 rows x 2 chunks of 64 B
        int row = lane >> 1;
        int ch = lane & 1;
        const uint4* rp = (const uint4*)(hp + row * 136 + ch * 32);
        uint4 v0 = rp[0], v1 = rp[1], v2 = rp[2], v3 = rp[3];
        int gr = mb + row;
        if (gr < n) {
            uint4* op = (uint4*)(g2h + (size_t)gr * 32) + ch * 4;
            op[0] = v0; op[1] = v1; op[2] = v2; op[3] = v3;
        }
    }
}

extern "C" void kernel_launch(void* const* d_in, const int* in_sizes, int n_in,
                              void* d_out, int out_size, void* d_ws, size_t ws_size,
                              hipStream_t stream) {
    const float* x     = (const float*)d_in[0];
    const int*   edge  = (const int*)d_in[1];
    const float* W1s   = (const float*)d_in[2];
    const float* W1d   = (const float*)d_in[3];
    const float* att1s = (const float*)d_in[4];
    const float* att1d = (const float*)d_in[5];
    const float* b1    = (const float*)d_in[6];
    const float* W2s   = (const float*)d_in[7];
    const float* W2d   = (const float*)d_in[8];
    const float* att2s = (const float*)d_in[9];
    const float* att2d = (const float*)d_in[10];
    const float* b2    = (const float*)d_in[11];

    const int N = in_sizes[0] / 128;
    const int E = in_sizes[1] / 2;
    const int* srcI = edge;
    const int* dstI = edge + E;

    const int nbE = (E + 4095) / 4096;
    const int nbuckets = (N + 511) >> 9;
    const int gblk = (N + 63) / 64;

    size_t off = 0;
    auto alloc = [&](size_t bytes) {
        void* p = (char*)d_ws + off;
        off += (bytes + 255) & ~(size_t)255;
        return p;
    };
    int*      offs  = (int*)alloc((size_t)(N + 1) * 4);
    int*      srcs  = (int*)alloc((size_t)E * 4);
    int*      gh    = (int*)alloc(256 * 4);
    int*      bbase = (int*)alloc(257 * 4);
    int*      gcur  = (int*)alloc(256 * 4);
    float*    watt1 = (float*)alloc(128 * 4);
    float*    watt2 = (float*)alloc(128 * 4);
    uint4*    wp1   = (uint4*)alloc(4 * 8 * 64 * 16);        // packed W1s f16
    uint4*    wp2   = (uint4*)alloc(4 * 4 * 64 * 16);        // packed W2s f16
    float*    a_s   = (float*)alloc((size_t)N * 4);
    float*    a_d   = (float*)alloc((size_t)N * 4);
    float*    a_s2  = (float*)alloc((size_t)N * 4);
    float*    a_d2  = (float*)alloc((size_t)N * 4);
    unsigned* g1h   = (unsigned*)alloc((size_t)N * 128 * 2); // gemm1 out (gather), f16
    unsigned* g2h   = (unsigned*)alloc((size_t)N * 64 * 2);  // gemm2 out (gather), f16
    unsigned* pairs = (unsigned*)g2h;  // dead until agg_gemm writes g2h (bsort first)

    hipMemsetAsync(gh, 0, 256 * 4, stream);
    setup_kernel<<<nbE + 66, 256, 0, stream>>>(dstI, gh, E, nbE, W1s, wp1, W2s, wp2,
                                               W1d, att1d, watt1, W2d, att2d, watt2);
    bscan_kernel<<<1, 256, 0, stream>>>(gh, bbase, gcur, offs, N, E);
    scatter_gemm_kernel<<<nbE + gblk, 256, 0, stream>>>(srcI, dstI, gcur, pairs, E, nbE,
                                                        x, wp1, att1s, watt1, g1h, a_s, a_d, N);
    bsort_kernel<<<nbuckets, 512, 0, stream>>>(pairs, bbase, offs, srcs, N);
    agg_gemm_kernel<<<gblk, 512, 0, stream>>>(offs, srcs, g1h, a_s, a_d, b1,
                                              wp2, att2s, watt2, g2h, a_s2, a_d2, N);
    aggregate_kernel<64, false, false, true><<<(N + 7) / 8, 256, 0, stream>>>(
        offs, srcs, g2h, a_s2, a_d2, b2, d_out, N);
}